// Round 3
// baseline (1576.535 us; speedup 1.0000x reference)
//
#include <hip/hip_runtime.h>
#include <cstdint>
#include <cstddef>

#define DEV __device__ __forceinline__

// ---------------- problem constants ----------------
constexpr size_t W_TOT = 131712;   // meta-param count
constexpr size_t OFF_W1 = 0;       // [128][256]
constexpr size_t OFF_B1 = 32768;   // [256]
constexpr size_t OFF_W2 = 33024;   // [256][256]
constexpr size_t OFF_B2 = 98560;   // [256]
constexpr size_t OFF_W3 = 98816;   // [256][128]
constexpr size_t OFF_B3 = 131584;  // [128]

// ---------------- workspace layout (floats) ----------------
constexpr size_t P_LOSS   = 0;        // [4][64]
constexpr size_t P_WA     = 256;      // [8][32]
constexpr size_t P_WU     = 512;      // [8][32]
constexpr size_t P_FT     = 768;      // [8] (pad to 1024)
constexpr size_t P_H2PI   = 1024;                 // [256][128]
constexpr size_t P_STRUCT = P_H2PI  + 32768;      // [256][128]
constexpr size_t P_ENC    = P_STRUCT+ 32768;      // [256][128]
constexpr size_t P_KEYS   = P_ENC   + 32768;      // [256][128]
constexpr size_t P_VALS   = P_KEYS  + 32768;      // [256][128]
constexpr size_t R0       = P_VALS  + 32768;      // big region (trans aliases chain)
// trans = R0 .. R0+4194304   ([256][16384], dead after k_rnn)
constexpr size_t R_Q12  = R0;             // [512][128]
constexpr size_t R_BA   = R0 + 65536;     // [512][256] scratch
constexpr size_t R_BB   = R0 + 196608;    // [512][256] scratch
constexpr size_t R_O312 = R0 + 327680;    // [512][256] o3 out (r1 rows 0-255, r2 rows 256-511)
constexpr size_t R_O3R3 = R0 + 458752;    // [256][256]
constexpr size_t R_O3R4 = R0 + 524288;    // [256][256]
constexpr size_t R_Q3   = R0 + 589824;    // [256][128]
constexpr size_t R_INF  = R0 + 622592;    // [256][128]
constexpr size_t R_Q4   = R0 + 655360;    // [256][128]
constexpr size_t R_SSE  = R0 + 688128;    // [256] (pad 1024)
constexpr size_t R_H1   = R0 + 690176;    // [256][256]
constexpr size_t R_H2   = R0 + 755712;    // [256][256]
constexpr size_t R_D1   = R0 + 821248;    // [256][256]
constexpr size_t R_D2   = R0 + 886784;    // [256][256]
constexpr size_t R_D3   = R0 + 952320;    // [256][128]

// ================= K0: zero loss partials =================
__global__ __launch_bounds__(256) void k_zero(float* __restrict__ p)
{
  p[threadIdx.x] = 0.f;
}

// ================= generic tiled GEMM with fused epilogues =================
// C[rows x OUT] = epi(A[rows x IN] @ W[IN x OUT] + bias)
// A is a 3-segment row source: [0,s1) from A1, [s1,s2) from A2, [s2,IN) scalar A3[row].
// wtr: W stored transposed (element (i,c) = W[c*ldw + i]).
// grid: (OUT/64, rows/64), 256 threads, 64x64 tile, K-chunk 64, 4x4 micro-tile.
// emode: 0 store(+act)  1 dec-loss(no store)  2 store + rel-loss(rows>=256,col<128)
//        3 pred_var->inf_s store + cons-loss  4 d3=(val-E1)*2/128 store  5 mask by E1>0 store
__global__ __launch_bounds__(256) void k_gemm(
    const float* __restrict__ A1, int lda1, int s1,
    const float* __restrict__ A2, int lda2, int s2,
    const float* __restrict__ A3,
    const float* __restrict__ W, int ldw, int wtr,
    const float* __restrict__ bias,
    float* __restrict__ C, int ldc,
    int IN, int act, int emode,
    const float* __restrict__ E1, const float* __restrict__ E2,
    float* __restrict__ lossPart, int slot,
    const float* __restrict__ irp)
{
  __shared__ float As[64][68];
  __shared__ float Ws[64][68];
  __shared__ float red[4];
  const int c0 = blockIdx.x * 64, r0 = blockIdx.y * 64;
  const int tid = threadIdx.x;
  const int tr = (tid >> 4) << 2;   // 4 rows
  const int tc = (tid & 15) << 2;   // 4 cols
  float acc[4][4] = {};

  for (int k0 = 0; k0 < IN; k0 += 64) {
    for (int idx = tid; idx < 4096; idx += 256) {
      const int i = idx & 63, r = idx >> 6;
      const int gi = k0 + i;
      float v;
      if (gi >= IN) v = 0.f;
      else if (gi < s1) v = A1[(size_t)(r0 + r) * lda1 + gi];
      else if (gi < s2) v = A2[(size_t)(r0 + r) * lda2 + (gi - s1)];
      else v = A3[r0 + r];
      As[i][r] = v;
    }
    if (!wtr) {
      for (int idx = tid; idx < 4096; idx += 256) {
        const int c = idx & 63, i = idx >> 6;
        const int gi = k0 + i;
        Ws[i][c] = (gi < IN) ? W[(size_t)gi * ldw + c0 + c] : 0.f;
      }
    } else {
      for (int idx = tid; idx < 4096; idx += 256) {
        const int i = idx & 63, c = idx >> 6;
        const int gi = k0 + i;
        Ws[i][c] = (gi < IN) ? W[(size_t)(c0 + c) * ldw + gi] : 0.f;
      }
    }
    __syncthreads();
#pragma unroll 16
    for (int i = 0; i < 64; ++i) {
      const float4 a = *reinterpret_cast<const float4*>(&As[i][tr]);
      const float4 w = *reinterpret_cast<const float4*>(&Ws[i][tc]);
      acc[0][0] = fmaf(a.x, w.x, acc[0][0]);
      acc[0][1] = fmaf(a.x, w.y, acc[0][1]);
      acc[0][2] = fmaf(a.x, w.z, acc[0][2]);
      acc[0][3] = fmaf(a.x, w.w, acc[0][3]);
      acc[1][0] = fmaf(a.y, w.x, acc[1][0]);
      acc[1][1] = fmaf(a.y, w.y, acc[1][1]);
      acc[1][2] = fmaf(a.y, w.z, acc[1][2]);
      acc[1][3] = fmaf(a.y, w.w, acc[1][3]);
      acc[2][0] = fmaf(a.z, w.x, acc[2][0]);
      acc[2][1] = fmaf(a.z, w.y, acc[2][1]);
      acc[2][2] = fmaf(a.z, w.z, acc[2][2]);
      acc[2][3] = fmaf(a.z, w.w, acc[2][3]);
      acc[3][0] = fmaf(a.w, w.x, acc[3][0]);
      acc[3][1] = fmaf(a.w, w.y, acc[3][1]);
      acc[3][2] = fmaf(a.w, w.z, acc[3][2]);
      acc[3][3] = fmaf(a.w, w.w, acc[3][3]);
    }
    __syncthreads();
  }

  float lsum = 0.f;
  if (emode == 1) {
#pragma unroll
    for (int rr = 0; rr < 4; ++rr)
#pragma unroll
      for (int cc = 0; cc < 4; ++cc) {
        const int row = r0 + tr + rr, col = c0 + tc + cc;
        const float d = acc[rr][cc] - E1[(size_t)row * 512 + col];
        lsum = fmaf(d, d, lsum);
      }
  } else if (emode == 3) {
    const float sig = 1.f / (1.f + expf(-irp[0]));
#pragma unroll
    for (int rr = 0; rr < 4; ++rr)
#pragma unroll
      for (int cc = 0; cc < 4; ++cc) {
        const int row = r0 + tr + rr, col = c0 + tc + cc;
        const float pv = acc[rr][cc] + bias[col];
        const float corr = E1[(size_t)row * 256 + col];
        const float dgs  = E2[(size_t)row * 256 + col];
        const float diff = (corr - dgs) * sig * pv;
        C[(size_t)row * ldc + col] = dgs + diff;
        lsum = fmaf(diff, diff, lsum);
      }
  } else {
#pragma unroll
    for (int rr = 0; rr < 4; ++rr)
#pragma unroll
      for (int cc = 0; cc < 4; ++cc) {
        const int row = r0 + tr + rr, col = c0 + tc + cc;
        float val = acc[rr][cc] + (bias ? bias[col] : 0.f);
        if (act) val = fmaxf(val, 0.f);
        if (emode == 4) val = (val - E1[(size_t)row * 128 + col]) * (2.f / 128.f);
        else if (emode == 5) val = (E1[(size_t)row * 256 + col] > 0.f) ? val : 0.f;
        C[(size_t)row * ldc + col] = val;
        if (emode == 2 && row >= 256 && col < 128) {
          const float d = val - E1[(size_t)(row - 256) * 128 + col];
          lsum = fmaf(d, d, lsum);
        }
      }
  }
  if (emode == 1 || emode == 2 || emode == 3) {
#pragma unroll
    for (int s = 32; s > 0; s >>= 1) lsum += __shfl_xor(lsum, s);
    if ((tid & 63) == 0) red[tid >> 6] = lsum;
    __syncthreads();
    if (tid == 0)
      lossPart[slot * 64 + blockIdx.y * gridDim.x + blockIdx.x] =
          red[0] + red[1] + red[2] + red[3];
  }
}

// ================= K1a: action MLP first two layers =================
__global__ __launch_bounds__(128) void k_pi_h2(
    const float* __restrict__ actions,
    const float* __restrict__ w1, const float* __restrict__ b1,
    const float* __restrict__ w2, const float* __restrict__ b2,
    float* __restrict__ h2out)
{
  const int row = blockIdx.x;
  const int j = threadIdx.x;
  __shared__ float a[32];
  __shared__ float h1[128];
  if (j < 32) a[j] = actions[row * 32 + j];
  __syncthreads();
  float acc = b1[j];
#pragma unroll
  for (int i = 0; i < 32; ++i) acc = fmaf(a[i], w1[i * 128 + j], acc);
  h1[j] = fmaxf(acc, 0.f);
  __syncthreads();
  float acc2 = b2[j];
#pragma unroll 8
  for (int i = 0; i < 128; ++i) acc2 = fmaf(h1[i], w2[i * 128 + j], acc2);
  h2out[row * 128 + j] = fmaxf(acc2, 0.f);
}

// ================= K1b: h2[256,128] @ W3[128,16384] =================
__global__ __launch_bounds__(256) void k_pi_trans(
    const float* __restrict__ h2,
    const float* __restrict__ w3, const float* __restrict__ b3,
    float* __restrict__ trans)
{
  const int col = blockIdx.x * 256 + threadIdx.x;
  const int r0 = blockIdx.y * 32;
  __shared__ float h2s[32][128];
  for (int idx = threadIdx.x; idx < 32 * 128; idx += 256)
    h2s[idx >> 7][idx & 127] = h2[(size_t)(r0 + (idx >> 7)) * 128 + (idx & 127)];
  __syncthreads();
  float acc[32];
#pragma unroll
  for (int r = 0; r < 32; ++r) acc[r] = 0.f;
  for (int i = 0; i < 128; i += 8) {
    float w[8];
#pragma unroll
    for (int c = 0; c < 8; ++c) w[c] = w3[(size_t)(i + c) * 16384 + col];
#pragma unroll
    for (int r = 0; r < 32; ++r) {
      float s = acc[r];
#pragma unroll
      for (int c = 0; c < 8; ++c) s = fmaf(h2s[r][i + c], w[c], s);
      acc[r] = s;
    }
  }
  const float bv = b3[col];
#pragma unroll
  for (int r = 0; r < 32; ++r)
    trans[(size_t)(r0 + r) * 16384 + col] = acc[r] + bv;
}

// ================= K2: sequential RNN scan =================
__global__ __launch_bounds__(512) void k_rnn(
    const float* __restrict__ trans, const float* __restrict__ rinit,
    float* __restrict__ structural)
{
  const int b = blockIdx.x;
  const int tid = threadIdx.x;
  const int j = tid & 127, seg = tid >> 7;
  __shared__ float h[128];
  __shared__ float part[4][128];
  __shared__ float ssq;
  if (tid < 128) h[tid] = rinit[tid];
  __syncthreads();
  if (tid < 64) {
    float v = h[tid] * h[tid] + h[tid + 64] * h[tid + 64];
#pragma unroll
    for (int s = 32; s > 0; s >>= 1) v += __shfl_xor(v, s);
    if (tid == 0) ssq = v;
  }
  __syncthreads();
  if (tid < 128) h[tid] /= fmaxf(sqrtf(ssq), 1e-12f);
  __syncthreads();

  for (int t = 0; t < 32; ++t) {
    const float* Tm = trans + ((size_t)(b * 32 + t) << 14);
    float acc = 0.f;
#pragma unroll
    for (int k = 0; k < 32; ++k) {
      const int i = seg * 32 + k;
      acc = fmaf(h[i], Tm[(size_t)i * 128 + j], acc);
    }
    part[seg][j] = acc;
    __syncthreads();
    if (tid < 128) {
      float r = fmaxf(part[0][j] + part[1][j] + part[2][j] + part[3][j], 0.f);
      part[0][j] = r;
    }
    __syncthreads();
    if (tid < 64) {
      float v = part[0][tid] * part[0][tid] + part[0][tid + 64] * part[0][tid + 64];
#pragma unroll
      for (int s = 32; s > 0; s >>= 1) v += __shfl_xor(v, s);
      if (tid == 0) ssq = v;
    }
    __syncthreads();
    if (tid < 128) {
      const float nv = part[0][j] / fmaxf(sqrtf(ssq), 1e-12f);
      h[j] = nv;
      structural[(size_t)(b * 32 + t) * 128 + j] = nv;
    }
    __syncthreads();
  }
}

// ================= k_sse: sse[r] = ||corr_e - enc||^2 =================
__global__ __launch_bounds__(256) void k_sse(
    const float* __restrict__ o3r3, const float* __restrict__ enc,
    float* __restrict__ sse)
{
  const int row = blockIdx.x * 4 + (threadIdx.x >> 6);
  const int lane = threadIdx.x & 63;
  float v = 0.f;
  for (int c = lane; c < 128; c += 64) {
    const float d = o3r3[(size_t)row * 256 + 128 + c] - enc[(size_t)row * 128 + c];
    v = fmaf(d, d, v);
  }
#pragma unroll
  for (int s = 32; s > 0; s >>= 1) v += __shfl_xor(v, s);
  if (lane == 0) sse[row] = v;
}

// ================= k_coef_hp: hp projection + closed-form scan coefficients =================
__global__ __launch_bounds__(256) void k_coef_hp(
    const float* __restrict__ finals, const float* __restrict__ enc,
    const float* __restrict__ w_hp,
    float* __restrict__ wA, float* __restrict__ wU, float* __restrict__ Ftot)
{
  const int r = threadIdx.x;  // 0..255 = b*32+t
  float a0 = 0.f, a1 = 0.f, a2 = 0.f;
  for (int i = 0; i < 256; ++i) {
    const float x = (i < 128) ? finals[(size_t)r * 256 + i]
                              : enc[(size_t)r * 128 + (i - 128)];
    a0 = fmaf(x, w_hp[i * 3 + 0], a0);
    a1 = fmaf(x, w_hp[i * 3 + 1], a1);
    a2 = fmaf(x, w_hp[i * 3 + 2], a2);
  }
  __shared__ float lr[256], sf[256], sb[256];
  lr[r] = a0;
  sf[r] = 1.f / (1.f + expf(-a1));
  sb[r] = 1.f / (1.f + expf(-a2));
  __syncthreads();
  if (r < 8) {
    const int b = r;
    float cB = 1.f, cF = 1.f, Bv = 1.f;
    wU[b * 32 + 31] = lr[b * 32 + 31];
    wA[b * 32 + 31] = lr[b * 32 + 31];
    for (int t = 30; t >= 0; --t) {
      cB = sb[b * 32 + t + 1] * cB;
      cF = sf[b * 32 + t + 1] * cF;
      Bv = cF + sb[b * 32 + t + 1] * Bv;
      wU[b * 32 + t] = lr[b * 32 + t] * cB;
      wA[b * 32 + t] = lr[b * 32 + t] * Bv;
    }
    float ft = 1.f;
    for (int t = 0; t < 32; ++t) ft *= sf[b * 32 + t];
    Ftot[b] = ft;
  }
}

// ================= k_outer: weighted outer-product accumulation =================
__global__ __launch_bounds__(256) void k_outer(
    const float* __restrict__ L, int Lld,
    const float* __restrict__ D, int Dld,
    const float* __restrict__ P,
    const float* __restrict__ wA, const float* __restrict__ wU,
    const float* __restrict__ Ftot,
    float* __restrict__ out, size_t regionOff, int J)
{
  const int b = blockIdx.x;
  const int i0 = blockIdx.y * 32;
  const int tid = threadIdx.x;
  __shared__ float wAk[32][33], wUk[32][33];
  for (int idx = tid; idx < 1024; idx += 256) {
    const int t = idx >> 5, ii = idx & 31;
    const float kv = L[(size_t)(b * 32 + t) * Lld + i0 + ii];
    wAk[t][ii] = wA[b * 32 + t] * kv;
    wUk[t][ii] = wU[b * 32 + t] * kv;
  }
  __syncthreads();
  const int j = (J == 256) ? tid : (tid & 127);
  const int g = (J == 256) ? 0 : (tid >> 7);
  const int span = (J == 256) ? 32 : 16;
  const int iBeg = g * span;
  float dv[32];
#pragma unroll
  for (int t = 0; t < 32; ++t) dv[t] = D[(size_t)(b * 32 + t) * Dld + j];
  const float ft = Ftot[b];
  float* ob = out + 1 + (size_t)b * (2 * W_TOT);
  for (int ii = iBeg; ii < iBeg + span; ++ii) {
    float aA = 0.f, aU = 0.f;
#pragma unroll
    for (int t = 0; t < 32; ++t) {
      aA = fmaf(wAk[t][ii], dv[t], aA);
      aU = fmaf(wUk[t][ii], dv[t], aU);
    }
    const int i = i0 + ii;
    const size_t w = regionOff + (size_t)i * J + j;
    ob[w] = ft * P[(size_t)i * J + j] - aA;
    ob[W_TOT + w] = aU;
  }
}

// ================= k_bias: bias regions =================
__global__ __launch_bounds__(256) void k_bias(
    const float* __restrict__ d1s, const float* __restrict__ d2s,
    const float* __restrict__ d3s,
    const float* __restrict__ mb1, const float* __restrict__ mb2,
    const float* __restrict__ mb3,
    const float* __restrict__ wA, const float* __restrict__ wU,
    const float* __restrict__ Ftot, float* __restrict__ out)
{
  const int b = blockIdx.x;
  const int tid = threadIdx.x;
  const float ft = Ftot[b];
  float* ob = out + 1 + (size_t)b * (2 * W_TOT);
  for (int idx = tid; idx < 640; idx += 256) {
    const float* D; int ld, j; size_t off; float pv;
    if (idx < 256)      { D = d1s; ld = 256; j = idx;       off = OFF_B1; pv = mb1[j]; }
    else if (idx < 512) { D = d2s; ld = 256; j = idx - 256; off = OFF_B2; pv = mb2[j]; }
    else                { D = d3s; ld = 128; j = idx - 512; off = OFF_B3; pv = mb3[j]; }
    float aA = 0.f, aU = 0.f;
#pragma unroll
    for (int t = 0; t < 32; ++t) {
      const float dv = D[(size_t)(b * 32 + t) * ld + j];
      aA = fmaf(wA[b * 32 + t], dv, aA);
      aU = fmaf(wU[b * 32 + t], dv, aU);
    }
    ob[off + j] = ft * pv - aA;
    ob[W_TOT + off + j] = aU;
  }
}

// ================= k_final =================
__global__ __launch_bounds__(64) void k_final(
    const float* __restrict__ lossPart, float* __restrict__ out)
{
  const int tid = threadIdx.x;
  __shared__ float s[4];
  if (tid < 4) {
    float acc = 0.f;
    for (int w = 0; w < 64; ++w) acc += lossPart[tid * 64 + w];
    s[tid] = acc;
  }
  __syncthreads();
  if (tid == 0) {
    const float i1 = 1.f / (256.f * 512.f);  // B*T*DSENS
    const float i2 = 1.f / (256.f * 128.f);  // B*T*DS
    out[0] = s[0] * i1 + 2.f * s[1] * i2 + s[2] * i2 + s[3] * i1;
  }
}

// ================= launch =================
extern "C" void kernel_launch(void* const* d_in, const int* in_sizes, int n_in,
                              void* d_out, int out_size, void* d_ws, size_t ws_size,
                              hipStream_t stream)
{
  const float* sensory = (const float*)d_in[0];
  const float* actions = (const float*)d_in[1];
  const float* enc_w = (const float*)d_in[2];
  const float* dec_w = (const float*)d_in[3];
  const float* pi_w1 = (const float*)d_in[4];
  const float* pi_b1 = (const float*)d_in[5];
  const float* pi_w2 = (const float*)d_in[6];
  const float* pi_b2 = (const float*)d_in[7];
  const float* pi_w3 = (const float*)d_in[8];
  const float* pi_b3 = (const float*)d_in[9];
  const float* rinit = (const float*)d_in[10];
  const float* wq = (const float*)d_in[11];
  const float* wk = (const float*)d_in[12];
  const float* wv = (const float*)d_in[13];
  const float* w_hp = (const float*)d_in[14];
  const float* mw1 = (const float*)d_in[15]; const float* mb1 = (const float*)d_in[16];
  const float* mw2 = (const float*)d_in[17]; const float* mb2 = (const float*)d_in[18];
  const float* mw3 = (const float*)d_in[19]; const float* mb3 = (const float*)d_in[20];
  const float* ow1 = (const float*)d_in[21]; const float* ob1 = (const float*)d_in[22];
  const float* ow2 = (const float*)d_in[23]; const float* ob2 = (const float*)d_in[24];
  const float* ow3 = (const float*)d_in[25]; const float* ob3 = (const float*)d_in[26];
  const float* vw1 = (const float*)d_in[27]; const float* vb1 = (const float*)d_in[28];
  const float* vw2 = (const float*)d_in[29]; const float* vb2 = (const float*)d_in[30];
  const float* vw3 = (const float*)d_in[31]; const float* vb3 = (const float*)d_in[32];
  const float* ir  = (const float*)d_in[33];

  float* ws  = (float*)d_ws;
  float* out = (float*)d_out;

  float* lossP = ws + P_LOSS;
  float* wA = ws + P_WA; float* wU = ws + P_WU; float* Ft = ws + P_FT;
  float* h2pi = ws + P_H2PI;
  float* structural = ws + P_STRUCT;
  float* enc  = ws + P_ENC;
  float* keys = ws + P_KEYS;
  float* vals = ws + P_VALS;
  float* trans = ws + R0;
  float* q12  = ws + R_Q12;
  float* BA   = ws + R_BA;
  float* BB   = ws + R_BB;
  float* o312 = ws + R_O312;
  float* o3r3 = ws + R_O3R3;
  float* o3r4 = ws + R_O3R4;
  float* q3   = ws + R_Q3;
  float* infS = ws + R_INF;
  float* q4   = ws + R_Q4;
  float* sse  = ws + R_SSE;
  float* h1s  = ws + R_H1;
  float* h2s  = ws + R_H2;
  float* d1s  = ws + R_D1;
  float* d2s  = ws + R_D2;
  float* d3s  = ws + R_D3;

  const float* NUL = nullptr;
#define GEMM(gx, gy, A1, lda1, s1, A2, lda2, s2, A3, W, ldw, wtr, bias, C, ldc, IN, act, emode, E1, E2, slot) \
  hipLaunchKernelGGL(k_gemm, dim3(gx, gy), dim3(256), 0, stream, \
                     A1, lda1, s1, A2, lda2, s2, A3, W, ldw, wtr, bias, C, ldc, \
                     IN, act, emode, E1, E2, lossP, slot, ir)

  hipLaunchKernelGGL(k_zero, dim3(1), dim3(256), 0, stream, lossP);
  hipLaunchKernelGGL(k_pi_h2, dim3(256), dim3(128), 0, stream,
                     actions, pi_w1, pi_b1, pi_w2, pi_b2, h2pi);
  hipLaunchKernelGGL(k_pi_trans, dim3(64, 8), dim3(256), 0, stream,
                     h2pi, pi_w3, pi_b3, trans);
  hipLaunchKernelGGL(k_rnn, dim3(8), dim3(512), 0, stream, trans, rinit, structural);

  // enc = sensory @ enc_w
  GEMM(2, 4, sensory, 512, 512, NUL, 0, 512, NUL, enc_w, 128, 0, NUL, enc, 128, 512, 0, 0, NUL, NUL, 0);
  // q1 = structural @ wq_top ; q2 = enc @ wq_bot  (batched rows 0-255 / 256-511)
  GEMM(2, 4, structural, 128, 128, NUL, 0, 128, NUL, wq, 128, 0, NUL, q12, 128, 128, 0, 0, NUL, NUL, 0);
  GEMM(2, 4, enc, 128, 128, NUL, 0, 128, NUL, wq + 128 * 128, 128, 0, NUL, q12 + 256 * 128, 128, 128, 0, 0, NUL, NUL, 0);
  // r1+r2 batched m/o chain (512 rows)
  GEMM(4, 8, q12, 128, 128, NUL, 0, 128, NUL, mw1, 256, 0, mb1, BA, 256, 128, 1, 0, NUL, NUL, 0);
  GEMM(4, 8, BA, 256, 256, NUL, 0, 256, NUL, mw2, 256, 0, mb2, BB, 256, 256, 1, 0, NUL, NUL, 0);
  GEMM(2, 8, BB, 256, 256, NUL, 0, 256, NUL, mw3, 128, 0, mb3, BA, 128, 256, 0, 0, NUL, NUL, 0);
  GEMM(4, 8, BA, 128, 128, NUL, 0, 128, NUL, ow1, 256, 0, ob1, BB, 256, 128, 1, 0, NUL, NUL, 0);
  GEMM(4, 8, BB, 256, 256, NUL, 0, 256, NUL, ow2, 256, 0, ob2, BA, 256, 256, 1, 0, NUL, NUL, 0);
  // o3 with rel-loss epilogue (rows>=256, cols<128 vs structural) -> slot 1
  GEMM(4, 8, BA, 256, 256, NUL, 0, 256, NUL, ow3, 256, 0, ob3, o312, 256, 256, 0, 2, structural, NUL, 1);
  // gen loss: dec_enc(r1) @ dec_w vs sensory -> slot 0
  GEMM(8, 4, o312 + 128, 256, 128, NUL, 0, 128, NUL, dec_w, 512, 0, NUL, BB, 512, 128, 0, 1, sensory, NUL, 0);
  // q3 = [dgs | enc] @ wq
  GEMM(2, 4, o312, 256, 128, enc, 128, 256, NUL, wq, 128, 0, NUL, q3, 128, 256, 0, 0, NUL, NUL, 0);
  // r3 chain (256 rows)
  GEMM(4, 4, q3, 128, 128, NUL, 0, 128, NUL, mw1, 256, 0, mb1, BA, 256, 128, 1, 0, NUL, NUL, 0);
  GEMM(4, 4, BA, 256, 256, NUL, 0, 256, NUL, mw2, 256, 0, mb2, BB, 256, 256, 1, 0, NUL, NUL, 0);
  GEMM(2, 4, BB, 256, 256, NUL, 0, 256, NUL, mw3, 128, 0, mb3, BA, 128, 256, 0, 0, NUL, NUL, 0);
  GEMM(4, 4, BA, 128, 128, NUL, 0, 128, NUL, ow1, 256, 0, ob1, BB, 256, 128, 1, 0, NUL, NUL, 0);
  GEMM(4, 4, BB, 256, 256, NUL, 0, 256, NUL, ow2, 256, 0, ob2, BA, 256, 256, 1, 0, NUL, NUL, 0);
  GEMM(4, 4, BA, 256, 256, NUL, 0, 256, NUL, ow3, 256, 0, ob3, o3r3, 256, 256, 0, 0, NUL, NUL, 0);
  // sse
  hipLaunchKernelGGL(k_sse, dim3(64), dim3(256), 0, stream, o3r3, enc, sse);
  // pred_var MLP: vin = [corr_s | dgs | sse], with inf_s+cons epilogue on v3 -> slot 2
  GEMM(4, 4, o3r3, 256, 128, o312, 256, 256, sse, vw1, 256, 0, vb1, BA, 256, 257, 1, 0, NUL, NUL, 0);
  GEMM(4, 4, BA, 256, 256, NUL, 0, 256, NUL, vw2, 256, 0, vb2, BB, 256, 256, 1, 0, NUL, NUL, 0);
  GEMM(2, 4, BB, 256, 256, NUL, 0, 256, NUL, vw3, 128, 0, vb3, infS, 128, 256, 0, 3, o3r3, o312, 2);
  // q4 = inf_s @ wq_top
  GEMM(2, 4, infS, 128, 128, NUL, 0, 128, NUL, wq, 128, 0, NUL, q4, 128, 128, 0, 0, NUL, NUL, 0);
  // r4 chain (256 rows)
  GEMM(4, 4, q4, 128, 128, NUL, 0, 128, NUL, mw1, 256, 0, mb1, BA, 256, 128, 1, 0, NUL, NUL, 0);
  GEMM(4, 4, BA, 256, 256, NUL, 0, 256, NUL, mw2, 256, 0, mb2, BB, 256, 256, 1, 0, NUL, NUL, 0);
  GEMM(2, 4, BB, 256, 256, NUL, 0, 256, NUL, mw3, 128, 0, mb3, BA, 128, 256, 0, 0, NUL, NUL, 0);
  GEMM(4, 4, BA, 128, 128, NUL, 0, 128, NUL, ow1, 256, 0, ob1, BB, 256, 128, 1, 0, NUL, NUL, 0);
  GEMM(4, 4, BB, 256, 256, NUL, 0, 256, NUL, ow2, 256, 0, ob2, BA, 256, 256, 1, 0, NUL, NUL, 0);
  GEMM(4, 4, BA, 256, 256, NUL, 0, 256, NUL, ow3, 256, 0, ob3, o3r4, 256, 256, 0, 0, NUL, NUL, 0);
  // inf loss -> slot 3
  GEMM(8, 4, o3r4 + 128, 256, 128, NUL, 0, 128, NUL, dec_w, 512, 0, NUL, BB, 512, 128, 0, 1, sensory, NUL, 3);
  // keys / vals from joint = [final_s | enc]
  GEMM(2, 4, o3r4, 256, 128, enc, 128, 256, NUL, wk, 128, 0, NUL, keys, 128, 256, 0, 0, NUL, NUL, 0);
  GEMM(2, 4, o3r4, 256, 128, enc, 128, 256, NUL, wv, 128, 0, NUL, vals, 128, 256, 0, 0, NUL, NUL, 0);
  // hp + scan coefficients
  hipLaunchKernelGGL(k_coef_hp, dim3(1), dim3(256), 0, stream, o3r4, enc, w_hp, wA, wU, Ft);
  // meta forward + backward (layerwise)
  GEMM(4, 4, keys, 128, 128, NUL, 0, 128, NUL, mw1, 256, 0, mb1, h1s, 256, 128, 1, 0, NUL, NUL, 0);
  GEMM(4, 4, h1s, 256, 256, NUL, 0, 256, NUL, mw2, 256, 0, mb2, h2s, 256, 256, 1, 0, NUL, NUL, 0);
  GEMM(2, 4, h2s, 256, 256, NUL, 0, 256, NUL, mw3, 128, 0, mb3, d3s, 128, 256, 0, 4, vals, NUL, 0);
  GEMM(4, 4, d3s, 128, 128, NUL, 0, 128, NUL, mw3, 128, 1, NUL, d2s, 256, 128, 0, 5, h2s, NUL, 0);
  GEMM(4, 4, d2s, 256, 256, NUL, 0, 256, NUL, mw2, 256, 1, NUL, d1s, 256, 256, 0, 5, h1s, NUL, 0);
  // TTT write step
  hipLaunchKernelGGL(k_outer, dim3(8, 4), dim3(256), 0, stream,
                     keys, 128, d1s, 256, mw1, wA, wU, Ft, out, OFF_W1, 256);
  hipLaunchKernelGGL(k_outer, dim3(8, 8), dim3(256), 0, stream,
                     h1s, 256, d2s, 256, mw2, wA, wU, Ft, out, OFF_W2, 256);
  hipLaunchKernelGGL(k_outer, dim3(8, 8), dim3(256), 0, stream,
                     h2s, 256, d3s, 128, mw3, wA, wU, Ft, out, OFF_W3, 128);
  hipLaunchKernelGGL(k_bias, dim3(8), dim3(256), 0, stream,
                     d1s, d2s, d3s, mb1, mb2, mb3, wA, wU, Ft, out);
  hipLaunchKernelGGL(k_final, dim3(1), dim3(64), 0, stream, lossP, out);
#undef GEMM
}

// Round 4
// 249.210 us; speedup vs baseline: 6.3261x; 6.3261x over previous
//
#include <hip/hip_runtime.h>
#include <cstdint>
#include <cstddef>

#define DEV __device__ __forceinline__

// ---------------- problem constants ----------------
constexpr size_t W_TOT = 131712;
constexpr size_t OFF_W1 = 0;       // [128][256]
constexpr size_t OFF_B1 = 32768;   // [256]
constexpr size_t OFF_W2 = 33024;   // [256][256]
constexpr size_t OFF_B2 = 98560;   // [256]
constexpr size_t OFF_W3 = 98816;   // [256][128]
constexpr size_t OFF_B3 = 131584;  // [128]

constexpr int OPS = 272;           // LDS activation row stride

// ---------------- workspace layout (floats) ----------------
constexpr size_t P_LOSS = 0;                    // [4][256]
constexpr size_t P_WA   = 1024;                 // [8][32]
constexpr size_t P_WU   = 1280;                 // [8][32]
constexpr size_t P_FT   = 1536;                 // [8]
constexpr size_t P_HP   = 2048;                 // [256][4]
constexpr size_t P_H2PI = 4096;                 // [256][128]
constexpr size_t P_ENC  = P_H2PI + 32768;       // [256][128]
constexpr size_t P_DGS  = P_ENC + 32768;        // [256][128]
constexpr size_t P_INF  = P_DGS + 32768;        // [256][128]
constexpr size_t P_KEYS = P_INF + 32768;        // [256][128]
constexpr size_t P_VALS = P_KEYS + 32768;       // [256][128]
constexpr size_t P_D3   = P_VALS + 32768;       // [256][128]
constexpr size_t P_H1   = P_D3 + 32768;         // [256][256]
constexpr size_t P_H2   = P_H1 + 65536;         // [256][256]
constexpr size_t P_D1   = P_H2 + 65536;         // [256][256]
constexpr size_t P_D2   = P_D1 + 65536;         // [256][256]
constexpr size_t P_STRUCT = P_D2 + 65536;       // [256][128]
constexpr size_t P_TRANS  = P_STRUCT + 32768;   // [256][16384]

DEV float sigm(float x) { return 1.f / (1.f + expf(-x)); }

// per-WG scalar reduce (256 threads = 4 waves)
DEV float wgsum(float v, float* red) {
#pragma unroll
  for (int s = 32; s > 0; s >>= 1) v += __shfl_xor(v, s);
  if ((threadIdx.x & 63) == 0) red[threadIdx.x >> 6] = v;
  __syncthreads();
  const float t = red[0] + red[1] + red[2] + red[3];
  __syncthreads();
  return t;
}

// ---------------- generic streamed dense layer ----------------
// ROWS rows of activations in LDS; weights streamed from global (L2-hot).
// 256 threads. OUT>128: 1-2 cols/thread. OUT==128: 2-way split-K + LDS combine.
template<int ROWS>
DEV void layT(int IN, int OUT,
              const float* __restrict__ W, int ldw, int wtr,
              const float* __restrict__ bias,
              const float* __restrict__ in, int ips,
              float* __restrict__ out, int ops, int relu,
              float* __restrict__ scr)
{
  const int tid = (int)threadIdx.x;
  if (OUT > 128) {
    for (int j = tid; j < OUT; j += 256) {
      float acc[ROWS];
#pragma unroll
      for (int r = 0; r < ROWS; ++r) acc[r] = 0.f;
      int i = 0;
      for (; i + 8 <= IN; i += 8) {
        float w[8];
#pragma unroll
        for (int u = 0; u < 8; ++u)
          w[u] = wtr ? W[(size_t)j * ldw + i + u] : W[(size_t)(i + u) * ldw + j];
#pragma unroll
        for (int u = 0; u < 8; ++u)
#pragma unroll
          for (int r = 0; r < ROWS; ++r)
            acc[r] = fmaf(in[r * ips + i + u], w[u], acc[r]);
      }
      for (; i < IN; ++i) {
        const float wv = wtr ? W[(size_t)j * ldw + i] : W[(size_t)i * ldw + j];
#pragma unroll
        for (int r = 0; r < ROWS; ++r) acc[r] = fmaf(in[r * ips + i], wv, acc[r]);
      }
#pragma unroll
      for (int r = 0; r < ROWS; ++r) {
        float v = acc[r] + (bias ? bias[j] : 0.f);
        if (relu) v = fmaxf(v, 0.f);
        out[r * ops + j] = v;
      }
    }
  } else {
    const int j = tid & 127, seg = tid >> 7;
    const int half = IN >> 1;
    const int ib = seg * half, ie = seg ? IN : half;
    float acc[ROWS];
#pragma unroll
    for (int r = 0; r < ROWS; ++r) acc[r] = 0.f;
    int i = ib;
    for (; i + 8 <= ie; i += 8) {
      float w[8];
#pragma unroll
      for (int u = 0; u < 8; ++u)
        w[u] = wtr ? W[(size_t)j * ldw + i + u] : W[(size_t)(i + u) * ldw + j];
#pragma unroll
      for (int u = 0; u < 8; ++u)
#pragma unroll
        for (int r = 0; r < ROWS; ++r)
          acc[r] = fmaf(in[r * ips + i + u], w[u], acc[r]);
    }
    for (; i < ie; ++i) {
      const float wv = wtr ? W[(size_t)j * ldw + i] : W[(size_t)i * ldw + j];
#pragma unroll
      for (int r = 0; r < ROWS; ++r) acc[r] = fmaf(in[r * ips + i], wv, acc[r]);
    }
#pragma unroll
    for (int r = 0; r < ROWS; ++r) scr[(seg * ROWS + r) * 128 + j] = acc[r];
    __syncthreads();
    if (seg == 0) {
#pragma unroll
      for (int r = 0; r < ROWS; ++r) {
        float v = scr[r * 128 + j] + scr[(ROWS + r) * 128 + j] + (bias ? bias[j] : 0.f);
        if (relu) v = fmaxf(v, 0.f);
        out[r * ops + j] = v;
      }
    }
  }
  __syncthreads();
}

// [A(128)|B(128)] @ W[256x128] -> out[128]; seg0 does A-half, seg1 B-half.
DEV void lay2cat(const float* __restrict__ A, const float* __restrict__ B,
                 const float* __restrict__ W, float* __restrict__ out,
                 float* __restrict__ scr)
{
  const int tid = (int)threadIdx.x, j = tid & 127, seg = tid >> 7;
  const float* src = seg ? B : A;
  const int base = seg * 128;
  float acc = 0.f;
  for (int i = 0; i < 128; i += 8) {
    float w[8];
#pragma unroll
    for (int u = 0; u < 8; ++u) w[u] = W[(size_t)(base + i + u) * 128 + j];
#pragma unroll
    for (int u = 0; u < 8; ++u) acc = fmaf(src[i + u], w[u], acc);
  }
  scr[seg * 128 + j] = acc;
  __syncthreads();
  if (seg == 0) out[j] = scr[j] + scr[128 + j];
  __syncthreads();
}

// x[128] @ W[128x128] -> out[128]; 2-way split-K.
DEV void lay1q(const float* __restrict__ x, const float* __restrict__ W,
               float* __restrict__ out, float* __restrict__ scr)
{
  const int tid = (int)threadIdx.x, j = tid & 127, seg = tid >> 7;
  float acc = 0.f;
  for (int i = seg * 64; i < seg * 64 + 64; i += 8) {
    float w[8];
#pragma unroll
    for (int u = 0; u < 8; ++u) w[u] = W[(size_t)(i + u) * 128 + j];
#pragma unroll
    for (int u = 0; u < 8; ++u) acc = fmaf(x[i + u], w[u], acc);
  }
  scr[seg * 128 + j] = acc;
  __syncthreads();
  if (seg == 0) out[j] = scr[j] + scr[128 + j];
  __syncthreads();
}

// de[128] @ dec_w[128x512] vs sens[512] -> per-thread squared-error partial
DEV float decloss(const float* __restrict__ de, const float* __restrict__ dec_w,
                  const float* __restrict__ sens)
{
  float ls = 0.f;
  for (int j = (int)threadIdx.x; j < 512; j += 256) {
    float acc = 0.f;
    for (int i = 0; i < 128; i += 8) {
      float w[8];
#pragma unroll
      for (int u = 0; u < 8; ++u) w[u] = dec_w[(size_t)(i + u) * 512 + j];
#pragma unroll
      for (int u = 0; u < 8; ++u) acc = fmaf(de[i + u], w[u], acc);
    }
    const float d = acc - sens[j];
    ls = fmaf(d, d, ls);
  }
  return ls;
}

// ================= K1a: action MLP first two layers =================
__global__ __launch_bounds__(128) void k_pi_h2(
    const float* __restrict__ actions,
    const float* __restrict__ w1, const float* __restrict__ b1,
    const float* __restrict__ w2, const float* __restrict__ b2,
    float* __restrict__ h2out)
{
  const int row = blockIdx.x;
  const int j = threadIdx.x;
  __shared__ float a[32];
  __shared__ float h1[128];
  if (j < 32) a[j] = actions[row * 32 + j];
  __syncthreads();
  float acc = b1[j];
#pragma unroll
  for (int i = 0; i < 32; ++i) acc = fmaf(a[i], w1[i * 128 + j], acc);
  h1[j] = fmaxf(acc, 0.f);
  __syncthreads();
  float acc2 = b2[j];
#pragma unroll 8
  for (int i = 0; i < 128; ++i) acc2 = fmaf(h1[i], w2[i * 128 + j], acc2);
  h2out[row * 128 + j] = fmaxf(acc2, 0.f);
}

// ================= K1b: h2[256,128] @ W3[128,16384] =================
__global__ __launch_bounds__(256) void k_pi_trans(
    const float* __restrict__ h2,
    const float* __restrict__ w3, const float* __restrict__ b3,
    float* __restrict__ trans)
{
  const int col = blockIdx.x * 256 + threadIdx.x;
  const int r0 = blockIdx.y * 32;
  __shared__ float h2s[32][128];
  for (int idx = threadIdx.x; idx < 32 * 128; idx += 256)
    h2s[idx >> 7][idx & 127] = h2[(size_t)(r0 + (idx >> 7)) * 128 + (idx & 127)];
  __syncthreads();
  float acc[32];
#pragma unroll
  for (int r = 0; r < 32; ++r) acc[r] = 0.f;
  for (int i = 0; i < 128; i += 8) {
    float w[8];
#pragma unroll
    for (int c = 0; c < 8; ++c) w[c] = w3[(size_t)(i + c) * 16384 + col];
#pragma unroll
    for (int r = 0; r < 32; ++r) {
      float s = acc[r];
#pragma unroll
      for (int c = 0; c < 8; ++c) s = fmaf(h2s[r][i + c], w[c], s);
      acc[r] = s;
    }
  }
  const float bv = b3[col];
#pragma unroll
  for (int r = 0; r < 32; ++r)
    trans[(size_t)(r0 + r) * 16384 + col] = acc[r] + bv;
}

// ================= K2: RNN scan with next-step prefetch =================
__global__ __launch_bounds__(512) void k_rnn(
    const float* __restrict__ trans, const float* __restrict__ rinit,
    float* __restrict__ structural)
{
  const int b = blockIdx.x;
  const int tid = threadIdx.x;
  const int j = tid & 127, seg = tid >> 7;
  __shared__ float h[128];
  __shared__ float part[4][128];
  __shared__ float ssq;
  if (tid < 128) h[tid] = rinit[tid];
  __syncthreads();
  if (tid < 64) {
    float v = h[tid] * h[tid] + h[tid + 64] * h[tid + 64];
#pragma unroll
    for (int s = 32; s > 0; s >>= 1) v += __shfl_xor(v, s);
    if (tid == 0) ssq = v;
  }
  __syncthreads();
  if (tid < 128) h[tid] /= fmaxf(sqrtf(ssq), 1e-12f);
  __syncthreads();

  float cur[32], nxt[32];
  {
    const float* T0 = trans + ((size_t)(b * 32) << 14);
#pragma unroll
    for (int k = 0; k < 32; ++k) cur[k] = T0[(size_t)(seg * 32 + k) * 128 + j];
  }
  for (int t = 0; t < 32; ++t) {
    if (t < 31) {
      const float* Tn = trans + ((size_t)(b * 32 + t + 1) << 14);
#pragma unroll
      for (int k = 0; k < 32; ++k) nxt[k] = Tn[(size_t)(seg * 32 + k) * 128 + j];
    }
    float acc = 0.f;
#pragma unroll
    for (int k = 0; k < 32; ++k) acc = fmaf(h[seg * 32 + k], cur[k], acc);
    part[seg][j] = acc;
    __syncthreads();
    if (tid < 128) {
      float r = fmaxf(part[0][j] + part[1][j] + part[2][j] + part[3][j], 0.f);
      part[0][j] = r;
    }
    __syncthreads();
    if (tid < 64) {
      float v = part[0][tid] * part[0][tid] + part[0][tid + 64] * part[0][tid + 64];
#pragma unroll
      for (int s = 32; s > 0; s >>= 1) v += __shfl_xor(v, s);
      if (tid == 0) ssq = v;
    }
    __syncthreads();
    if (tid < 128) {
      const float nv = part[0][j] / fmaxf(sqrtf(ssq), 1e-12f);
      h[j] = nv;
      structural[(size_t)(b * 32 + t) * 128 + j] = nv;
    }
    __syncthreads();
    if (t < 31) {
#pragma unroll
      for (int k = 0; k < 32; ++k) cur[k] = nxt[k];
    }
  }
}

// ================= kA: enc + retrieve1 + retrieve2 + gen/rel losses =================
// one WG per row g; 2 virtual rows (r1 from struct, r2 from enc) share weight stream
__global__ __launch_bounds__(256) void kA(
    const float* __restrict__ sensory, const float* __restrict__ structural_,
    const float* __restrict__ enc_w, const float* __restrict__ wq,
    const float* __restrict__ dec_w,
    const float* __restrict__ mw1, const float* __restrict__ mb1,
    const float* __restrict__ mw2, const float* __restrict__ mb2,
    const float* __restrict__ mw3, const float* __restrict__ mb3,
    const float* __restrict__ ow1, const float* __restrict__ ob1,
    const float* __restrict__ ow2, const float* __restrict__ ob2,
    const float* __restrict__ ow3, const float* __restrict__ ob3,
    float* __restrict__ ws_enc, float* __restrict__ ws_dgs,
    float* __restrict__ lossPart)
{
  const int g = blockIdx.x, tid = threadIdx.x;
  __shared__ float sens[512], sRow[128], eRow[128];
  __shared__ float actA[2 * OPS], actB[2 * OPS];
  __shared__ float scr[4 * 128];
  __shared__ float red[4];
  for (int i = tid; i < 512; i += 256) sens[i] = sensory[(size_t)g * 512 + i];
  if (tid < 128) sRow[tid] = structural_[(size_t)g * 128 + tid];
  __syncthreads();
  // enc row (IN=512 -> 128, split-K 2)
  {
    const int j = tid & 127, seg = tid >> 7;
    float acc = 0.f;
    for (int i = seg * 256; i < seg * 256 + 256; i += 8) {
      float w[8];
#pragma unroll
      for (int u = 0; u < 8; ++u) w[u] = enc_w[(size_t)(i + u) * 128 + j];
#pragma unroll
      for (int u = 0; u < 8; ++u) acc = fmaf(sens[i + u], w[u], acc);
    }
    scr[seg * 128 + j] = acc;
    __syncthreads();
    if (seg == 0) {
      const float v = scr[j] + scr[128 + j];
      eRow[j] = v;
      ws_enc[(size_t)g * 128 + j] = v;
    }
    __syncthreads();
  }
  // q layer: vrow0 = struct @ wq_top, vrow1 = enc @ wq_bot
  {
    const int j = tid & 127, seg = tid >> 7;
    float a0 = 0.f, a1 = 0.f;
    for (int i = seg * 64; i < seg * 64 + 64; ++i) {
      a0 = fmaf(sRow[i], wq[(size_t)i * 128 + j], a0);
      a1 = fmaf(eRow[i], wq[(size_t)(128 + i) * 128 + j], a1);
    }
    scr[(seg * 2 + 0) * 128 + j] = a0;
    scr[(seg * 2 + 1) * 128 + j] = a1;
    __syncthreads();
    if (seg == 0) {
      actA[j]       = scr[0 * 128 + j] + scr[2 * 128 + j];
      actA[OPS + j] = scr[1 * 128 + j] + scr[3 * 128 + j];
    }
    __syncthreads();
  }
  layT<2>(128, 256, mw1, 256, 0, mb1, actA, OPS, actB, OPS, 1, scr);
  layT<2>(256, 256, mw2, 256, 0, mb2, actB, OPS, actA, OPS, 1, scr);
  layT<2>(256, 128, mw3, 128, 0, mb3, actA, OPS, actB, OPS, 0, scr);
  layT<2>(128, 256, ow1, 256, 0, ob1, actB, OPS, actA, OPS, 1, scr);
  layT<2>(256, 256, ow2, 256, 0, ob2, actA, OPS, actB, OPS, 1, scr);
  layT<2>(256, 256, ow3, 256, 0, ob3, actB, OPS, actA, OPS, 0, scr);
  if (tid < 128) ws_dgs[(size_t)g * 128 + tid] = actA[tid];
  float lrel = 0.f;
  if (tid < 128) {
    const float d = actA[OPS + tid] - sRow[tid];
    lrel = d * d;
  }
  const float relT = wgsum(lrel, red);
  if (tid == 0) lossPart[256 + g] = relT;
  const float lg = decloss(&actA[128], dec_w, sens);
  const float genT = wgsum(lg, red);
  if (tid == 0) lossPart[g] = genT;
}

// ================= kB: retrieve3 + sse + pred_var + inf_s + cons loss =================
__global__ __launch_bounds__(256) void kB(
    const float* __restrict__ ws_enc, const float* __restrict__ ws_dgs,
    const float* __restrict__ wq,
    const float* __restrict__ mw1, const float* __restrict__ mb1,
    const float* __restrict__ mw2, const float* __restrict__ mb2,
    const float* __restrict__ mw3, const float* __restrict__ mb3,
    const float* __restrict__ ow1, const float* __restrict__ ob1,
    const float* __restrict__ ow2, const float* __restrict__ ob2,
    const float* __restrict__ ow3, const float* __restrict__ ob3,
    const float* __restrict__ vw1, const float* __restrict__ vb1,
    const float* __restrict__ vw2, const float* __restrict__ vb2,
    const float* __restrict__ vw3, const float* __restrict__ vb3,
    const float* __restrict__ ir,
    float* __restrict__ ws_inf, float* __restrict__ lossPart)
{
  const int g = blockIdx.x, tid = threadIdx.x;
  __shared__ float eRow[128], dgsRow[128], cRow[128];
  __shared__ float actA[OPS], actB[OPS];
  __shared__ float scr[2 * 128];
  __shared__ float red[4];
  if (tid < 128) eRow[tid] = ws_enc[(size_t)g * 128 + tid];
  else dgsRow[tid - 128] = ws_dgs[(size_t)g * 128 + (tid - 128)];
  __syncthreads();
  lay2cat(dgsRow, eRow, wq, actA, scr);                       // q3
  layT<1>(128, 256, mw1, 256, 0, mb1, actA, OPS, actB, OPS, 1, scr);
  layT<1>(256, 256, mw2, 256, 0, mb2, actB, OPS, actA, OPS, 1, scr);
  layT<1>(256, 128, mw3, 128, 0, mb3, actA, OPS, actB, OPS, 0, scr);
  layT<1>(128, 256, ow1, 256, 0, ob1, actB, OPS, actA, OPS, 1, scr);
  layT<1>(256, 256, ow2, 256, 0, ob2, actA, OPS, actB, OPS, 1, scr);
  layT<1>(256, 256, ow3, 256, 0, ob3, actB, OPS, actA, OPS, 0, scr);  // [corr|corr_e]
  float ls = 0.f;
  if (tid < 128) {
    cRow[tid] = actA[tid];
    const float d = actA[128 + tid] - eRow[tid];
    ls = d * d;
  }
  const float sseV = wgsum(ls, red);
  // v1: [corr(128)|dgs(128)|sse] (257) -> 256, relu
  {
    const int j = tid;
    float acc = vb1[j];
    for (int i = 0; i < 128; i += 8) {
      float w[8];
#pragma unroll
      for (int u = 0; u < 8; ++u) w[u] = vw1[(size_t)(i + u) * 256 + j];
#pragma unroll
      for (int u = 0; u < 8; ++u) acc = fmaf(cRow[i + u], w[u], acc);
    }
    for (int i = 0; i < 128; i += 8) {
      float w[8];
#pragma unroll
      for (int u = 0; u < 8; ++u) w[u] = vw1[(size_t)(128 + i + u) * 256 + j];
#pragma unroll
      for (int u = 0; u < 8; ++u) acc = fmaf(dgsRow[i + u], w[u], acc);
    }
    acc = fmaf(sseV, vw1[(size_t)256 * 256 + j], acc);
    actB[j] = fmaxf(acc, 0.f);
  }
  __syncthreads();
  layT<1>(256, 256, vw2, 256, 0, vb2, actB, OPS, actA, OPS, 1, scr);
  layT<1>(256, 128, vw3, 128, 0, vb3, actA, OPS, actB, OPS, 0, scr);  // pv in actB[0:128]
  const float sig = sigm(ir[0]);
  float lc = 0.f;
  if (tid < 128) {
    const float diff = (cRow[tid] - dgsRow[tid]) * sig * actB[tid];
    ws_inf[(size_t)g * 128 + tid] = dgsRow[tid] + diff;
    lc = diff * diff;
  }
  const float consT = wgsum(lc, red);
  if (tid == 0) lossPart[512 + g] = consT;
}

// ================= kC: retrieve4 + inf loss + keys/vals/hp =================
__global__ __launch_bounds__(256) void kC(
    const float* __restrict__ sensory,
    const float* __restrict__ ws_enc, const float* __restrict__ ws_inf,
    const float* __restrict__ wq, const float* __restrict__ dec_w,
    const float* __restrict__ mw1, const float* __restrict__ mb1,
    const float* __restrict__ mw2, const float* __restrict__ mb2,
    const float* __restrict__ mw3, const float* __restrict__ mb3,
    const float* __restrict__ ow1, const float* __restrict__ ob1,
    const float* __restrict__ ow2, const float* __restrict__ ob2,
    const float* __restrict__ ow3, const float* __restrict__ ob3,
    const float* __restrict__ wk, const float* __restrict__ wv,
    const float* __restrict__ w_hp,
    float* __restrict__ ws_keys, float* __restrict__ ws_vals,
    float* __restrict__ ws_hp, float* __restrict__ lossPart)
{
  const int g = blockIdx.x, tid = threadIdx.x;
  __shared__ float sens[512], eRow[128], infRow[128];
  __shared__ float actA[OPS], actB[OPS];
  __shared__ float scr[2 * 128];
  __shared__ float red[4];
  for (int i = tid; i < 512; i += 256) sens[i] = sensory[(size_t)g * 512 + i];
  if (tid < 128) eRow[tid] = ws_enc[(size_t)g * 128 + tid];
  else infRow[tid - 128] = ws_inf[(size_t)g * 128 + (tid - 128)];
  __syncthreads();
  lay1q(infRow, wq, actA, scr);                               // q4
  layT<1>(128, 256, mw1, 256, 0, mb1, actA, OPS, actB, OPS, 1, scr);
  layT<1>(256, 256, mw2, 256, 0, mb2, actB, OPS, actA, OPS, 1, scr);
  layT<1>(256, 128, mw3, 128, 0, mb3, actA, OPS, actB, OPS, 0, scr);
  layT<1>(128, 256, ow1, 256, 0, ob1, actB, OPS, actA, OPS, 1, scr);
  layT<1>(256, 256, ow2, 256, 0, ob2, actA, OPS, actB, OPS, 1, scr);
  layT<1>(256, 256, ow3, 256, 0, ob3, actB, OPS, actA, OPS, 0, scr);  // [finalS|inf_e]
  const float li = decloss(&actA[128], dec_w, sens);
  const float infT = wgsum(li, red);
  if (tid == 0) lossPart[768 + g] = infT;
  lay2cat(actA, eRow, wk, ws_keys + (size_t)g * 128, scr);
  lay2cat(actA, eRow, wv, ws_vals + (size_t)g * 128, scr);
  // hp: 3 outputs, one wave each
  const int c = tid >> 6, l = tid & 63;
  float acc = 0.f;
  if (c < 3) {
    for (int i = l; i < 256; i += 64) {
      const float x = (i < 128) ? actA[i] : eRow[i - 128];
      acc = fmaf(x, w_hp[i * 3 + c], acc);
    }
  }
#pragma unroll
  for (int s = 32; s > 0; s >>= 1) acc += __shfl_xor(acc, s);
  if (c < 3 && l == 0) ws_hp[(size_t)g * 4 + c] = acc;
}

// ================= kD: meta fwd/bwd (blocks 0-255) + coef scan (block 256) =================
__global__ __launch_bounds__(256) void kD(
    const float* __restrict__ ws_keys, const float* __restrict__ ws_vals,
    const float* __restrict__ ws_hp,
    const float* __restrict__ mw1, const float* __restrict__ mb1,
    const float* __restrict__ mw2, const float* __restrict__ mb2,
    const float* __restrict__ mw3, const float* __restrict__ mb3,
    float* __restrict__ ws_h1, float* __restrict__ ws_h2,
    float* __restrict__ ws_d1, float* __restrict__ ws_d2, float* __restrict__ ws_d3,
    float* __restrict__ wA, float* __restrict__ wU, float* __restrict__ Ft)
{
  const int tid = threadIdx.x;
  __shared__ float kRow[128], vRow[128];
  __shared__ float actA[256], actB[256], d3R[128], d2R[256];
  __shared__ float scr[2 * 128];
  __shared__ float lr[256], sf[256], sb[256];
  if (blockIdx.x == 256) {
    lr[tid] = ws_hp[(size_t)tid * 4 + 0];
    sf[tid] = sigm(ws_hp[(size_t)tid * 4 + 1]);
    sb[tid] = sigm(ws_hp[(size_t)tid * 4 + 2]);
    __syncthreads();
    if (tid < 8) {
      const int b = tid;
      float cB = 1.f, cF = 1.f, Bv = 1.f;
      wU[b * 32 + 31] = lr[b * 32 + 31];
      wA[b * 32 + 31] = lr[b * 32 + 31];
      for (int t = 30; t >= 0; --t) {
        cB = sb[b * 32 + t + 1] * cB;
        cF = sf[b * 32 + t + 1] * cF;
        Bv = cF + sb[b * 32 + t + 1] * Bv;
        wU[b * 32 + t] = lr[b * 32 + t] * cB;
        wA[b * 32 + t] = lr[b * 32 + t] * Bv;
      }
      float ft = 1.f;
      for (int t = 0; t < 32; ++t) ft *= sf[b * 32 + t];
      Ft[b] = ft;
    }
    return;
  }
  const int g = blockIdx.x;
  if (tid < 128) kRow[tid] = ws_keys[(size_t)g * 128 + tid];
  else vRow[tid - 128] = ws_vals[(size_t)g * 128 + (tid - 128)];
  __syncthreads();
  layT<1>(128, 256, mw1, 256, 0, mb1, kRow, 128, actA, 256, 1, scr);
  ws_h1[(size_t)g * 256 + tid] = actA[tid];
  layT<1>(256, 256, mw2, 256, 0, mb2, actA, 256, actB, 256, 1, scr);
  ws_h2[(size_t)g * 256 + tid] = actB[tid];
  layT<1>(256, 128, mw3, 128, 0, mb3, actB, 256, d3R, 128, 0, scr);
  if (tid < 128) {
    const float d = (d3R[tid] - vRow[tid]) * (2.f / 128.f);
    d3R[tid] = d;
    ws_d3[(size_t)g * 128 + tid] = d;
  }
  __syncthreads();
  // d2 = relu'(h2) * (d3 @ mw3^T)
  {
    const int j = tid;
    float acc = 0.f;
    for (int i = 0; i < 128; i += 8) {
      float w[8];
#pragma unroll
      for (int u = 0; u < 8; ++u) w[u] = mw3[(size_t)j * 128 + i + u];
#pragma unroll
      for (int u = 0; u < 8; ++u) acc = fmaf(w[u], d3R[i + u], acc);
    }
    const float v = (actB[j] > 0.f) ? acc : 0.f;
    d2R[j] = v;
    ws_d2[(size_t)g * 256 + j] = v;
  }
  __syncthreads();
  // d1 = relu'(h1) * (d2 @ mw2^T)
  {
    const int j = tid;
    float acc = 0.f;
    for (int i = 0; i < 256; i += 8) {
      float w[8];
#pragma unroll
      for (int u = 0; u < 8; ++u) w[u] = mw2[(size_t)j * 256 + i + u];
#pragma unroll
      for (int u = 0; u < 8; ++u) acc = fmaf(w[u], d2R[i + u], acc);
    }
    ws_d1[(size_t)g * 256 + j] = (actA[j] > 0.f) ? acc : 0.f;
  }
}

// ================= kW: outer products + bias + final (single launch) =================
DEV void outer_body(const float* __restrict__ L, int Lld,
                    const float* __restrict__ D, int Dld,
                    const float* __restrict__ P,
                    const float* __restrict__ wA, const float* __restrict__ wU,
                    const float* __restrict__ Ftot,
                    float* __restrict__ out, size_t regionOff, int J,
                    int b, int i0, float* __restrict__ wAk, float* __restrict__ wUk)
{
  const int tid = threadIdx.x;
  for (int idx = tid; idx < 1024; idx += 256) {
    const int t = idx >> 5, ii = idx & 31;
    const float kv = L[(size_t)(b * 32 + t) * Lld + i0 + ii];
    wAk[t * 33 + ii] = wA[b * 32 + t] * kv;
    wUk[t * 33 + ii] = wU[b * 32 + t] * kv;
  }
  __syncthreads();
  const int j = (J == 256) ? tid : (tid & 127);
  const int g2 = (J == 256) ? 0 : (tid >> 7);
  const int span = (J == 256) ? 32 : 16;
  const int iBeg = g2 * span;
  float dv[32];
#pragma unroll
  for (int t = 0; t < 32; ++t) dv[t] = D[(size_t)(b * 32 + t) * Dld + j];
  const float ft = Ftot[b];
  float* ob = out + 1 + (size_t)b * (2 * W_TOT);
  for (int ii = iBeg; ii < iBeg + span; ++ii) {
    float aA = 0.f, aU = 0.f;
#pragma unroll
    for (int t = 0; t < 32; ++t) {
      aA = fmaf(wAk[t * 33 + ii], dv[t], aA);
      aU = fmaf(wUk[t * 33 + ii], dv[t], aU);
    }
    const int i = i0 + ii;
    const size_t w = regionOff + (size_t)i * J + j;
    ob[w] = ft * P[(size_t)i * J + j] - aA;
    ob[W_TOT + w] = aU;
  }
}

__global__ __launch_bounds__(256) void kW(
    const float* __restrict__ keys, const float* __restrict__ h1,
    const float* __restrict__ h2, const float* __restrict__ d1,
    const float* __restrict__ d2, const float* __restrict__ d3,
    const float* __restrict__ mw1, const float* __restrict__ mb1,
    const float* __restrict__ mw2, const float* __restrict__ mb2,
    const float* __restrict__ mw3, const float* __restrict__ mb3,
    const float* __restrict__ wA, const float* __restrict__ wU,
    const float* __restrict__ Ft, const float* __restrict__ lossPart,
    float* __restrict__ out)
{
  __shared__ float wAk[32 * 33], wUk[32 * 33];
  __shared__ float red[4];
  const int bid = blockIdx.x;
  const int tid = threadIdx.x;
  if (bid < 32) {
    outer_body(keys, 128, d1, 256, mw1, wA, wU, Ft, out, OFF_W1, 256,
               bid >> 2, (bid & 3) * 32, wAk, wUk);
  } else if (bid < 96) {
    const int x = bid - 32;
    outer_body(h1, 256, d2, 256, mw2, wA, wU, Ft, out, OFF_W2, 256,
               x >> 3, (x & 7) * 32, wAk, wUk);
  } else if (bid < 160) {
    const int x = bid - 96;
    outer_body(h2, 256, d3, 128, mw3, wA, wU, Ft, out, OFF_W3, 128,
               x >> 3, (x & 7) * 32, wAk, wUk);
  } else if (bid < 168) {
    const int b = bid - 160;
    const float ft = Ft[b];
    float* ob = out + 1 + (size_t)b * (2 * W_TOT);
    for (int idx = tid; idx < 640; idx += 256) {
      const float* D; int ld, j; size_t off; float pv;
      if (idx < 256)      { D = d1; ld = 256; j = idx;       off = OFF_B1; pv = mb1[j]; }
      else if (idx < 512) { D = d2; ld = 256; j = idx - 256; off = OFF_B2; pv = mb2[j]; }
      else                { D = d3; ld = 128; j = idx - 512; off = OFF_B3; pv = mb3[j]; }
      float aA = 0.f, aU = 0.f;
#pragma unroll
      for (int t = 0; t < 32; ++t) {
        const float dv = D[(size_t)(b * 32 + t) * ld + j];
        aA = fmaf(wA[b * 32 + t], dv, aA);
        aU = fmaf(wU[b * 32 + t], dv, aU);
      }
      ob[off + j] = ft * pv - aA;
      ob[W_TOT + off + j] = aU;
    }
  } else {
    // final loss
    const int c = tid >> 6, l = tid & 63;
    float v = lossPart[c * 256 + l] + lossPart[c * 256 + 64 + l] +
              lossPart[c * 256 + 128 + l] + lossPart[c * 256 + 192 + l];
#pragma unroll
    for (int s = 32; s > 0; s >>= 1) v += __shfl_xor(v, s);
    if (l == 0) red[c] = v;
    __syncthreads();
    if (tid == 0) {
      const float i1 = 1.f / (256.f * 512.f);
      const float i2 = 1.f / (256.f * 128.f);
      out[0] = red[0] * i1 + 2.f * red[1] * i2 + red[2] * i2 + red[3] * i1;
    }
  }
}

// ================= launch =================
extern "C" void kernel_launch(void* const* d_in, const int* in_sizes, int n_in,
                              void* d_out, int out_size, void* d_ws, size_t ws_size,
                              hipStream_t stream)
{
  const float* sensory = (const float*)d_in[0];
  const float* actions = (const float*)d_in[1];
  const float* enc_w = (const float*)d_in[2];
  const float* dec_w = (const float*)d_in[3];
  const float* pi_w1 = (const float*)d_in[4];
  const float* pi_b1 = (const float*)d_in[5];
  const float* pi_w2 = (const float*)d_in[6];
  const float* pi_b2 = (const float*)d_in[7];
  const float* pi_w3 = (const float*)d_in[8];
  const float* pi_b3 = (const float*)d_in[9];
  const float* rinit = (const float*)d_in[10];
  const float* wq = (const float*)d_in[11];
  const float* wk = (const float*)d_in[12];
  const float* wv = (const float*)d_in[13];
  const float* w_hp = (const float*)d_in[14];
  const float* mw1 = (const float*)d_in[15]; const float* mb1 = (const float*)d_in[16];
  const float* mw2 = (const float*)d_in[17]; const float* mb2 = (const float*)d_in[18];
  const float* mw3 = (const float*)d_in[19]; const float* mb3 = (const float*)d_in[20];
  const float* ow1 = (const float*)d_in[21]; const float* ob1 = (const float*)d_in[22];
  const float* ow2 = (const float*)d_in[23]; const float* ob2 = (const float*)d_in[24];
  const float* ow3 = (const float*)d_in[25]; const float* ob3 = (const float*)d_in[26];
  const float* vw1 = (const float*)d_in[27]; const float* vb1 = (const float*)d_in[28];
  const float* vw2 = (const float*)d_in[29]; const float* vb2 = (const float*)d_in[30];
  const float* vw3 = (const float*)d_in[31]; const float* vb3 = (const float*)d_in[32];
  const float* ir  = (const float*)d_in[33];

  float* ws  = (float*)d_ws;
  float* out = (float*)d_out;

  float* lossP = ws + P_LOSS;
  float* wA = ws + P_WA; float* wU = ws + P_WU; float* Ft = ws + P_FT;
  float* hp = ws + P_HP;
  float* h2pi = ws + P_H2PI;
  float* enc = ws + P_ENC;
  float* dgs = ws + P_DGS;
  float* inf = ws + P_INF;
  float* keys = ws + P_KEYS;
  float* vals = ws + P_VALS;
  float* d3s = ws + P_D3;
  float* h1s = ws + P_H1;
  float* h2s = ws + P_H2;
  float* d1s = ws + P_D1;
  float* d2s = ws + P_D2;
  float* structural = ws + P_STRUCT;
  float* trans = ws + P_TRANS;

  hipLaunchKernelGGL(k_pi_h2, dim3(256), dim3(128), 0, stream,
                     actions, pi_w1, pi_b1, pi_w2, pi_b2, h2pi);
  hipLaunchKernelGGL(k_pi_trans, dim3(64, 8), dim3(256), 0, stream,
                     h2pi, pi_w3, pi_b3, trans);
  hipLaunchKernelGGL(k_rnn, dim3(8), dim3(512), 0, stream, trans, rinit, structural);
  hipLaunchKernelGGL(kA, dim3(256), dim3(256), 0, stream,
                     sensory, structural, enc_w, wq, dec_w,
                     mw1, mb1, mw2, mb2, mw3, mb3,
                     ow1, ob1, ow2, ob2, ow3, ob3,
                     enc, dgs, lossP);
  hipLaunchKernelGGL(kB, dim3(256), dim3(256), 0, stream,
                     enc, dgs, wq,
                     mw1, mb1, mw2, mb2, mw3, mb3,
                     ow1, ob1, ow2, ob2, ow3, ob3,
                     vw1, vb1, vw2, vb2, vw3, vb3,
                     ir, inf, lossP);
  hipLaunchKernelGGL(kC, dim3(256), dim3(256), 0, stream,
                     sensory, enc, inf, wq, dec_w,
                     mw1, mb1, mw2, mb2, mw3, mb3,
                     ow1, ob1, ow2, ob2, ow3, ob3,
                     wk, wv, w_hp, keys, vals, hp, lossP);
  hipLaunchKernelGGL(kD, dim3(257), dim3(256), 0, stream,
                     keys, vals, hp, mw1, mb1, mw2, mb2, mw3, mb3,
                     h1s, h2s, d1s, d2s, d3s, wA, wU, Ft);
  hipLaunchKernelGGL(kW, dim3(169), dim3(256), 0, stream,
                     keys, h1s, h2s, d1s, d2s, d3s,
                     mw1, mb1, mw2, mb2, mw3, mb3,
                     wA, wU, Ft, lossP, out);
}